// Round 7
// baseline (850.976 us; speedup 1.0000x reference)
//
#include <hip/hip_runtime.h>
#include <stdint.h>

typedef __bf16 bf16_t;
typedef bf16_t bf16x4 __attribute__((ext_vector_type(4)));
typedef bf16_t bf16x8 __attribute__((ext_vector_type(8)));
typedef float f32x4 __attribute__((ext_vector_type(4)));

#define DIM 256
#define NNODES 50000
#define NPANEL 8           // 8 panels x 32 dims; one panel = 50000*32*2B = 3.2MB < 4MiB L2/XCD
#define PDIM 32

// ---------------- edge dtype detection (int64 vs int32), per-wave inline ----------------
__device__ __forceinline__ int detect_f64(const int* __restrict__ ei) {
    int v = ei[2 * (threadIdx.x & 63) + 1];
    unsigned long long m = __ballot(v == 0);
    return __popcll(m) > 32;
}

__device__ __forceinline__ int load_edge(const int* __restrict__ ei, int E, int f64,
                                         int which /*0=src,1=dst*/, int e) {
    int v = f64 ? ei[(size_t)which * 2 * E + 2 * (size_t)e]   // int64 low word (LE)
                : ei[(size_t)which * E + (size_t)e];
    return min(max(v, 0), NNODES - 1);
}

// ---------------- CSR build ----------------

__global__ void hist_kernel(const int* __restrict__ ei, int E, int* __restrict__ counts) {
    int f64 = detect_f64(ei);
    int e = blockIdx.x * blockDim.x + threadIdx.x;
    if (e < E) atomicAdd(&counts[load_edge(ei, E, f64, 1, e)], 1);
}

__global__ __launch_bounds__(256) void scanA_kernel(const int* __restrict__ counts,
                                                    int* __restrict__ offsets,
                                                    int* __restrict__ bsums, int n) {
    __shared__ int sm[256];
    int b = blockIdx.x, t = threadIdx.x;
    int idx = b * 256 + t;
    int v = (idx < n) ? counts[idx] : 0;
    sm[t] = v;
    __syncthreads();
    #pragma unroll
    for (int off = 1; off < 256; off <<= 1) {
        int u = (t >= off) ? sm[t - off] : 0;
        __syncthreads();
        sm[t] += u;
        __syncthreads();
    }
    if (idx < n) offsets[idx + 1] = sm[t];
    if (t == 255) bsums[b] = sm[255];
}

__global__ __launch_bounds__(256) void scanB_kernel(int* __restrict__ bsums, int nb) {
    __shared__ int sm[256];
    int t = threadIdx.x;
    int v = (t < nb) ? bsums[t] : 0;
    sm[t] = v;
    __syncthreads();
    #pragma unroll
    for (int off = 1; off < 256; off <<= 1) {
        int u = (t >= off) ? sm[t - off] : 0;
        __syncthreads();
        sm[t] += u;
        __syncthreads();
    }
    if (t < nb) bsums[t] = sm[t] - v;
}

__global__ __launch_bounds__(256) void scanC_kernel(const int* __restrict__ counts,
                                                    const int* __restrict__ bsums,
                                                    int* __restrict__ offsets,
                                                    float* __restrict__ dinv,
                                                    int* __restrict__ cursor, int n) {
    int b = blockIdx.x;
    int idx = b * 256 + threadIdx.x;
    if (idx == 0) offsets[0] = 0;
    if (idx < n) {
        int incl = offsets[idx + 1] + bsums[b];
        offsets[idx + 1] = incl;
        cursor[idx] = incl - counts[idx];
        dinv[idx] = rsqrtf((float)(counts[idx] + 1));  // +1 self-loop
    }
}

// csr_e[pos] = {src, norm_bits} packed 8B.
__global__ void scatter_kernel(const int* __restrict__ ei, int E,
                               const float* __restrict__ dinv, int* __restrict__ cursor,
                               int2* __restrict__ csr_e) {
    int f64 = detect_f64(ei);
    int e = blockIdx.x * blockDim.x + threadIdx.x;
    if (e < E) {
        int s = load_edge(ei, E, f64, 0, e);
        int d = load_edge(ei, E, f64, 1, e);
        int pos = atomicAdd(&cursor[d], 1);
        if (pos >= 0 && pos < E) {
            int2 v;
            v.x = s;
            v.y = __float_as_int(dinv[s] * dinv[d]);
            csr_e[pos] = v;
        }
    }
}

// ---------------- weight prep: fp32 W[k][n] -> fragment-order bf16 Wf ----------------

__global__ void convert_w_kernel(const float* __restrict__ W1, const float* __restrict__ W2,
                                 bf16_t* __restrict__ Wf1, bf16_t* __restrict__ Wf2) {
    const float* W = blockIdx.y ? W2 : W1;
    bf16_t* Wf = blockIdx.y ? Wf2 : Wf1;
    int k = blockIdx.x, n = threadIdx.x;      // read W[k][n] coalesced per block
    int s = k >> 5, quad = (k >> 3) & 3, j = k & 7;
    int nt = n >> 4, m = n & 15;
    Wf[s * 8192 + (nt * 64 + quad * 16 + m) * 8 + j] = (bf16_t)W[k * DIM + n];
}

// ---------------- GEMM: Hp[panel-major](bf16) = X[M,256] @ W ----------------
// Output panel-major: Hp[p][row][32dims], p = col>>5. (Identical to round-2 version, which
// passed correctness.) A input: fp32 row-major (layer 1) or bf16 panel-major (layer 2).

template <bool F32A>
__global__ __launch_bounds__(256, 4) void gemm_kernel(const void* __restrict__ Xv,
                                                      const bf16_t* __restrict__ Wf,
                                                      bf16_t* __restrict__ Hp, int tiles) {
    __shared__ bf16_t sB[8192];               // 256n x 32k slice, fragment order
    int tid = threadIdx.x;
    int wave = tid >> 6, lane = tid & 63;
    int m = lane & 15, quad = lane >> 4;
    int tile = blockIdx.x * 4 + wave;
    bool active = tile < tiles;
    int arow = (min(tile, tiles - 1)) * 16 + m;   // clamped; store predicated below

    f32x4 acc[16] = {};

    for (int s = 0; s < 8; s++) {
        __syncthreads();                      // protect previous slice's reads
        {
            const bf16x8* g = (const bf16x8*)Wf + s * 1024;
            bf16x8* d = (bf16x8*)sB;
            #pragma unroll
            for (int it = 0; it < 4; it++) d[tid + it * 256] = g[tid + it * 256];
        }
        __syncthreads();

        bf16x8 a;
        if (F32A) {
            const f32x4* xp = (const f32x4*)((const float*)Xv + (size_t)arow * DIM + s * 32 + quad * 8);
            f32x4 x0 = xp[0], x1 = xp[1];
            #pragma unroll
            for (int j = 0; j < 4; j++) { a[j] = (bf16_t)x0[j]; a[j + 4] = (bf16_t)x1[j]; }
        } else {
            // panel-major bf16: panel s, within-panel offset quad*8 (16B aligned)
            a = *(const bf16x8*)((const bf16_t*)Xv + ((size_t)s * NNODES + arow) * PDIM + quad * 8);
        }

        #pragma unroll
        for (int nt = 0; nt < 16; nt++) {
            bf16x8 b = *(const bf16x8*)(sB + nt * 512 + lane * 8);  // sequential: no conflicts
            acc[nt] = __builtin_amdgcn_mfma_f32_16x16x32_bf16(a, b, acc[nt], 0, 0, 0);
        }
    }

    if (active) {
        int rowb = tile * 16 + quad * 4;
        #pragma unroll
        for (int nt = 0; nt < 16; nt++) {
            size_t pbase = ((size_t)(nt >> 1) * NNODES) * PDIM + (nt & 1) * 16 + m;
            #pragma unroll
            for (int r = 0; r < 4; r++) {
                Hp[pbase + (size_t)(rowb + r) * PDIM] = (bf16_t)acc[nt][r];
            }
        }
    }
}

// ---------------- Aggregation: XCC-pinned panel queues, L2-resident gather ----------------
// Theory: H (25.6MB) can't be resident in any 4MiB per-XCD L2 while all XCDs gather from all
// of it -> ~200MB/aggregate served by the saturated L3/HBM path (~4.6 TB/s) -> 41us floor
// across all prior structures. Round 2's blockIdx%8 "panels" never pinned to real XCDs.
// Here: each block reads its REAL XCD id via s_getreg(HW_REG_XCC_ID=20) [verified m09] and
// pulls chunks ONLY for panel==xcd from a per-XCD atomic queue -> each XCD's L2 holds its
// 3.2MB panel; gathers become L2 hits. Work-stealing fallback (probe other queues when own
// is empty) guarantees completion even if XCC_ID were wrong (degrades to r2 perf, never
// wrong results). Inner loop identical to round-2 (passed correctness).

template <int OUT_BF16P>  // 1: bf16 panel-major out; 0: fp32 row-major out
__global__ __launch_bounds__(256) void aggregate_kernel(const bf16_t* __restrict__ Hp,
                                                        const int* __restrict__ offsets,
                                                        const int2* __restrict__ csr_e,
                                                        const float* __restrict__ dinv,
                                                        const float* __restrict__ bias,
                                                        void* __restrict__ outv,
                                                        int* __restrict__ qctr, int n) {
    __shared__ int s_t;
    const int CPP = (NNODES + 31) / 32;    // 1563 chunks of 32 nodes per panel
    int xcd;
    asm volatile("s_getreg_b32 %0, hwreg(20, 0, 32)" : "=s"(xcd));  // HW_REG_XCC_ID
    xcd &= 7;

    auto cvt = [](bf16x4 v) -> f32x4 {
        f32x4 r;
        #pragma unroll
        for (int j = 0; j < 4; j++) r[j] = (float)v[j];
        return r;
    };

    int probe = 0;
    while (probe < 8) {
        int q = (xcd + probe) & 7;
        if (threadIdx.x == 0) s_t = atomicAdd(&qctr[q], 1);
        __syncthreads();
        int t = s_t;
        __syncthreads();
        if (t >= CPP) { probe++; continue; }

        int p = q;                          // panel == this block's XCD
        int wave = threadIdx.x >> 6, lane = threadIdx.x & 63;
        int g = lane >> 3, c = lane & 7;
        int i = t * 32 + wave * 8 + g;
        if (i < n) {
            const bf16_t* Hpan = Hp + (size_t)p * ((size_t)NNODES * PDIM);
            float dii = dinv[i];
            f32x4 acc = cvt(*(const bf16x4*)(Hpan + (size_t)i * PDIM + c * 4)) * (dii * dii);
            int e0 = offsets[i], e1 = offsets[i + 1];

            for (int e = e0; e < e1; e += 8) {
                int2 ed;
                if (e + c < e1) {
                    ed = csr_e[e + c];
                } else {
                    ed.x = i;               // pad: self row (L2-hot), zero weight
                    ed.y = 0;
                }
                int s[8]; float w[8];
                #pragma unroll
                for (int j = 0; j < 8; j++) {
                    int srcLane = (lane & 56) + j;
                    s[j] = __shfl(ed.x, srcLane, 64);
                    w[j] = __uint_as_float((unsigned)__shfl(ed.y, srcLane, 64));
                }
                bf16x4 h[8];
                #pragma unroll
                for (int j = 0; j < 8; j++) {
                    h[j] = *(const bf16x4*)(Hpan + (size_t)s[j] * PDIM + c * 4);
                }
                #pragma unroll
                for (int j = 0; j < 8; j++) acc += cvt(h[j]) * w[j];
            }

            acc += *(const f32x4*)(bias + p * PDIM + c * 4);
            #pragma unroll
            for (int j = 0; j < 4; j++) acc[j] = fmaxf(acc[j], 0.0f);

            if (OUT_BF16P) {
                bf16x4 o;
                #pragma unroll
                for (int j = 0; j < 4; j++) o[j] = (bf16_t)acc[j];
                *(bf16x4*)((bf16_t*)outv + (size_t)p * NNODES * PDIM + (size_t)i * PDIM + c * 4) = o;
            } else {
                *(f32x4*)((float*)outv + (size_t)i * DIM + p * PDIM + c * 4) = acc;
            }
        }
    }
}

// ---------------- launch ----------------

extern "C" void kernel_launch(void* const* d_in, const int* in_sizes, int n_in,
                              void* d_out, int out_size, void* d_ws, size_t ws_size,
                              hipStream_t stream) {
    const float* x  = (const float*)d_in[0];
    const int*   ei = (const int*)d_in[1];
    const float* W1 = (const float*)d_in[2];
    const float* b1 = (const float*)d_in[3];
    const float* W2 = (const float*)d_in[4];
    const float* b2 = (const float*)d_in[5];
    float* out = (float*)d_out;

    const int n = NNODES;
    const int E = in_sizes[1] / 2;
    const int nb = (n + 255) / 256;

    char* ws = (char*)d_ws;
    size_t off = 0;
    auto alloc = [&](size_t bytes) -> char* {
        char* p = ws + off;
        off += (bytes + 255) & ~(size_t)255;
        return p;
    };
    float*  dinv     = (float*)alloc((size_t)n * 4);
    int*    counts   = (int*)alloc((size_t)n * 4);   // contiguous with qctr: one memset covers both
    int*    qctr     = (int*)alloc(256);             // 2 sets of 8 per-XCD queue counters
    int*    offsets  = (int*)alloc((size_t)(n + 1) * 4);
    int*    cursor   = (int*)alloc((size_t)n * 4);
    int*    bsums    = (int*)alloc((size_t)nb * 4);
    int2*   csr_e    = (int2*)alloc((size_t)E * 8);
    bf16_t* Wf1      = (bf16_t*)alloc((size_t)DIM * DIM * 2);
    bf16_t* Wf2      = (bf16_t*)alloc((size_t)DIM * DIM * 2);
    bf16_t* P        = (bf16_t*)alloc((size_t)n * DIM * 2);   // GEMM output, panel-major bf16
    bf16_t* X2       = (bf16_t*)alloc((size_t)n * DIM * 2);   // inter-layer act, panel-major bf16

    size_t cb = (((size_t)n * 4) + 255) & ~(size_t)255;
    hipMemsetAsync(counts, 0, cb + 256, stream);     // zeros counts AND both qctr sets

    hist_kernel<<<(E + 255) / 256, 256, 0, stream>>>(ei, E, counts);
    scanA_kernel<<<nb, 256, 0, stream>>>(counts, offsets, bsums, n);
    scanB_kernel<<<1, 256, 0, stream>>>(bsums, nb);
    scanC_kernel<<<nb, 256, 0, stream>>>(counts, bsums, offsets, dinv, cursor, n);
    scatter_kernel<<<(E + 255) / 256, 256, 0, stream>>>(ei, E, dinv, cursor, csr_e);

    convert_w_kernel<<<dim3(DIM, 2), DIM, 0, stream>>>(W1, W2, Wf1, Wf2);

    int tiles = (n + 15) / 16;                 // 3125 (exact: 50000 = 16*3125)
    int gemm_blocks = (tiles + 3) / 4;         // 782
    int agg_blocks = 2048;                     // persistent-ish; ~256 blocks per XCD

    gemm_kernel<true><<<gemm_blocks, 256, 0, stream>>>(x, Wf1, P, tiles);
    aggregate_kernel<1><<<agg_blocks, 256, 0, stream>>>(P, offsets, csr_e, dinv, b1, X2,
                                                        qctr, n);
    gemm_kernel<false><<<gemm_blocks, 256, 0, stream>>>(X2, Wf2, P, tiles);
    aggregate_kernel<0><<<agg_blocks, 256, 0, stream>>>(P, offsets, csr_e, dinv, b2, out,
                                                        qctr + 8, n);
}

// Round 8
// 258.214 us; speedup vs baseline: 3.2956x; 3.2956x over previous
//
#include <hip/hip_runtime.h>
#include <stdint.h>

typedef __bf16 bf16_t;
typedef bf16_t bf16x4 __attribute__((ext_vector_type(4)));
typedef bf16_t bf16x8 __attribute__((ext_vector_type(8)));
typedef float f32x4 __attribute__((ext_vector_type(4)));

#define DIM 256
#define NNODES 50000

// ---------------- edge dtype detection (int64 vs int32), per-wave inline ----------------
// int64 edges: odd 4B words are high halves == 0 for values < 2^31.
__device__ __forceinline__ int detect_f64(const int* __restrict__ ei) {
    int v = ei[2 * (threadIdx.x & 63) + 1];
    unsigned long long m = __ballot(v == 0);
    return __popcll(m) > 32;
}

__device__ __forceinline__ int load_edge(const int* __restrict__ ei, int E, int f64,
                                         int which /*0=src,1=dst*/, int e) {
    int v = f64 ? ei[(size_t)which * 2 * E + 2 * (size_t)e]   // int64 low word (LE)
                : ei[(size_t)which * E + (size_t)e];
    return min(max(v, 0), NNODES - 1);
}

// ---------------- CSR build ----------------

__global__ void hist_kernel(const int* __restrict__ ei, int E, int* __restrict__ counts) {
    int f64 = detect_f64(ei);
    int e = blockIdx.x * blockDim.x + threadIdx.x;
    if (e < E) atomicAdd(&counts[load_edge(ei, E, f64, 1, e)], 1);
}

__global__ __launch_bounds__(256) void scanA_kernel(const int* __restrict__ counts,
                                                    int* __restrict__ offsets,
                                                    int* __restrict__ bsums, int n) {
    __shared__ int sm[256];
    int b = blockIdx.x, t = threadIdx.x;
    int idx = b * 256 + t;
    int v = (idx < n) ? counts[idx] : 0;
    sm[t] = v;
    __syncthreads();
    #pragma unroll
    for (int off = 1; off < 256; off <<= 1) {
        int u = (t >= off) ? sm[t - off] : 0;
        __syncthreads();
        sm[t] += u;
        __syncthreads();
    }
    if (idx < n) offsets[idx + 1] = sm[t];
    if (t == 255) bsums[b] = sm[255];
}

__global__ __launch_bounds__(256) void scanB_kernel(int* __restrict__ bsums, int nb) {
    __shared__ int sm[256];
    int t = threadIdx.x;
    int v = (t < nb) ? bsums[t] : 0;
    sm[t] = v;
    __syncthreads();
    #pragma unroll
    for (int off = 1; off < 256; off <<= 1) {
        int u = (t >= off) ? sm[t - off] : 0;
        __syncthreads();
        sm[t] += u;
        __syncthreads();
    }
    if (t < nb) bsums[t] = sm[t] - v;
}

__global__ __launch_bounds__(256) void scanC_kernel(const int* __restrict__ counts,
                                                    const int* __restrict__ bsums,
                                                    int* __restrict__ offsets,
                                                    float* __restrict__ dinv,
                                                    int* __restrict__ cursor, int n) {
    int b = blockIdx.x;
    int idx = b * 256 + threadIdx.x;
    if (idx == 0) offsets[0] = 0;
    if (idx < n) {
        int incl = offsets[idx + 1] + bsums[b];
        offsets[idx + 1] = incl;
        cursor[idx] = incl - counts[idx];
        dinv[idx] = rsqrtf((float)(counts[idx] + 1));  // +1 self-loop
    }
}

// csr_e[pos] = {src, norm_bits} packed 8B.
__global__ void scatter_kernel(const int* __restrict__ ei, int E,
                               const float* __restrict__ dinv, int* __restrict__ cursor,
                               int2* __restrict__ csr_e) {
    int f64 = detect_f64(ei);
    int e = blockIdx.x * blockDim.x + threadIdx.x;
    if (e < E) {
        int s = load_edge(ei, E, f64, 0, e);
        int d = load_edge(ei, E, f64, 1, e);
        int pos = atomicAdd(&cursor[d], 1);
        if (pos >= 0 && pos < E) {
            int2 v;
            v.x = s;
            v.y = __float_as_int(dinv[s] * dinv[d]);
            csr_e[pos] = v;
        }
    }
}

// ---------------- weight prep: fp32 W[k][n] -> fragment-order bf16 Wf ----------------
// Wf layout: slice s = k>>5 (8 slices); frag f = nt*64 + quad*16 + m where
// n = nt*16+m, k = s*32 + quad*8 + j. Flat short index: s*8192 + f*8 + j.

__global__ void convert_w_kernel(const float* __restrict__ W1, const float* __restrict__ W2,
                                 bf16_t* __restrict__ Wf1, bf16_t* __restrict__ Wf2) {
    const float* W = blockIdx.y ? W2 : W1;
    bf16_t* Wf = blockIdx.y ? Wf2 : Wf1;
    int k = blockIdx.x, n = threadIdx.x;      // read W[k][n] coalesced per block
    int s = k >> 5, quad = (k >> 3) & 3, j = k & 7;
    int nt = n >> 4, m = n & 15;
    Wf[s * 8192 + (nt * 64 + quad * 16 + m) * 8 + j] = (bf16_t)W[k * DIM + n];
}

// ---------------- GEMM: H[M,256](bf16, row-major) = X[M,256] @ W ----------------
// 1 row-tile (16 rows) per wave, 4 waves/block -> 64 rows/block, grid = 782.
// W staged per 32-k slice in fragment order: 16 KB LDS, zero bank conflicts.

template <bool F32A>
__global__ __launch_bounds__(256, 4) void gemm_kernel(const void* __restrict__ Xv,
                                                      const bf16_t* __restrict__ Wf,
                                                      bf16_t* __restrict__ H, int tiles) {
    __shared__ bf16_t sB[8192];               // 256n x 32k slice, fragment order
    int tid = threadIdx.x;
    int wave = tid >> 6, lane = tid & 63;
    int m = lane & 15, quad = lane >> 4;
    int tile = blockIdx.x * 4 + wave;
    bool active = tile < tiles;
    int arow = (min(tile, tiles - 1)) * 16 + m;   // clamped; store predicated below

    f32x4 acc[16] = {};

    for (int s = 0; s < 8; s++) {
        __syncthreads();                      // protect previous slice's reads
        {
            const bf16x8* g = (const bf16x8*)Wf + s * 1024;
            bf16x8* d = (bf16x8*)sB;
            #pragma unroll
            for (int it = 0; it < 4; it++) d[tid + it * 256] = g[tid + it * 256];
        }
        __syncthreads();

        // A fragment: A[m=lane&15][k = s*32 + quad*8 + j]
        bf16x8 a;
        if (F32A) {
            const f32x4* xp = (const f32x4*)((const float*)Xv + (size_t)arow * DIM + s * 32 + quad * 8);
            f32x4 x0 = xp[0], x1 = xp[1];
            #pragma unroll
            for (int j = 0; j < 4; j++) { a[j] = (bf16_t)x0[j]; a[j + 4] = (bf16_t)x1[j]; }
        } else {
            a = *(const bf16x8*)((const bf16_t*)Xv + (size_t)arow * DIM + s * 32 + quad * 8);
        }

        #pragma unroll
        for (int nt = 0; nt < 16; nt++) {
            bf16x8 b = *(const bf16x8*)(sB + nt * 512 + lane * 8);  // sequential: no conflicts
            acc[nt] = __builtin_amdgcn_mfma_f32_16x16x32_bf16(a, b, acc[nt], 0, 0, 0);
        }
    }

    if (active) {
        int rowb = tile * 16 + quad * 4;
        #pragma unroll
        for (int nt = 0; nt < 16; nt++) {
            #pragma unroll
            for (int r = 0; r < 4; r++) {
                H[(size_t)(rowb + r) * DIM + nt * 16 + m] = (bf16_t)acc[nt][r];
            }
        }
    }
}

// ---------------- Aggregation: forced-depth gather pipeline ----------------
// Identical structure to round-5 (32-lane group per node, lane owns 8 dims, same-address
// edge-meta loads HW-broadcast, batches of 8 gathers) with ONE change: a
// __builtin_amdgcn_sched_barrier(0) fence between the gather-issue block and the consume
// block. Rounds 5/6 proved (VGPR_Count 32/36) that the compiler interleaved load->consume
// and kept only ~2 gathers in flight; the fence forces all 8 loads to issue first and stay
// live (h[8] = 32 VGPRs), giving 8 independent 512B-row gathers in flight per node-group.
// Decisive A/B for the latency theory: expect VGPR >= 64; if dur stays ~41us anyway, the
// aggregate is at a genuine gather-service ceiling.

template <int OUT_BF16>
__global__ __launch_bounds__(256) void aggregate_kernel(const bf16_t* __restrict__ H,
                                                        const int* __restrict__ offsets,
                                                        const int2* __restrict__ csr_e,
                                                        const float* __restrict__ dinv,
                                                        const float* __restrict__ bias,
                                                        void* __restrict__ outv, int n) {
    int wg = threadIdx.x >> 5;     // 8 node-groups per block
    int l = threadIdx.x & 31;      // lane in group: dims l*8 .. l*8+7
    int i = blockIdx.x * 8 + wg;
    if (i >= n) return;

    const char* Hb = (const char*)H;
    int doff = l * 16;

    auto cvt = [](bf16x4 v) -> f32x4 {
        f32x4 r;
        #pragma unroll
        for (int j = 0; j < 4; j++) r[j] = (float)v[j];
        return r;
    };
    auto lo4 = [](bf16x8 v) -> bf16x4 { return __builtin_shufflevector(v, v, 0, 1, 2, 3); };
    auto hi4 = [](bf16x8 v) -> bf16x4 { return __builtin_shufflevector(v, v, 4, 5, 6, 7); };

    float dii = dinv[i];
    bf16x8 selfv = *(const bf16x8*)(Hb + ((size_t)i << 9) + doff);
    f32x4 acc0 = cvt(lo4(selfv)) * (dii * dii);
    f32x4 acc1 = cvt(hi4(selfv)) * (dii * dii);

    int e0 = offsets[i], e1 = offsets[i + 1];
    int e = e0;
    for (; e + 8 <= e1; e += 8) {
        unsigned s[8]; float w[8];
        #pragma unroll
        for (int j = 0; j < 8; j++) {
            int2 t = csr_e[e + j];
            s[j] = min((unsigned)t.x, (unsigned)(NNODES - 1));
            w[j] = __int_as_float(t.y);
        }
        bf16x8 h[8];
        #pragma unroll
        for (int j = 0; j < 8; j++) {
            h[j] = *(const bf16x8*)(Hb + ((size_t)s[j] << 9) + doff);
        }
        __builtin_amdgcn_sched_barrier(0);   // all 8 gathers issued before any consume
        #pragma unroll
        for (int j = 0; j < 8; j++) {
            acc0 += cvt(lo4(h[j])) * w[j];
            acc1 += cvt(hi4(h[j])) * w[j];
        }
    }
    if (e < e1) {
        unsigned s[8]; float w[8];
        #pragma unroll
        for (int j = 0; j < 8; j++) {
            bool valid = (e + j) < e1;
            int2 t = csr_e[valid ? e + j : e];   // e < e1 so csr_e[e] is safe
            if (!valid) { t.x = i; t.y = 0; }    // pad: self row (L1-hot), zero weight
            s[j] = min((unsigned)t.x, (unsigned)(NNODES - 1));
            w[j] = __int_as_float(t.y);
        }
        bf16x8 h[8];
        #pragma unroll
        for (int j = 0; j < 8; j++) {
            h[j] = *(const bf16x8*)(Hb + ((size_t)s[j] << 9) + doff);
        }
        __builtin_amdgcn_sched_barrier(0);   // all 8 gathers issued before any consume
        #pragma unroll
        for (int j = 0; j < 8; j++) {
            acc0 += cvt(lo4(h[j])) * w[j];
            acc1 += cvt(hi4(h[j])) * w[j];
        }
    }

    const f32x4* bp = (const f32x4*)(bias + l * 8);
    acc0 += bp[0];
    acc1 += bp[1];
    #pragma unroll
    for (int j = 0; j < 4; j++) {
        acc0[j] = fmaxf(acc0[j], 0.0f);
        acc1[j] = fmaxf(acc1[j], 0.0f);
    }

    if (OUT_BF16) {
        bf16x8 o;
        #pragma unroll
        for (int j = 0; j < 4; j++) { o[j] = (bf16_t)acc0[j]; o[j + 4] = (bf16_t)acc1[j]; }
        *(bf16x8*)((bf16_t*)outv + (size_t)i * DIM + l * 8) = o;
    } else {
        float* op = (float*)outv + (size_t)i * DIM + l * 8;
        *(f32x4*)op = acc0;
        *(f32x4*)(op + 4) = acc1;
    }
}

// ---------------- launch ----------------

extern "C" void kernel_launch(void* const* d_in, const int* in_sizes, int n_in,
                              void* d_out, int out_size, void* d_ws, size_t ws_size,
                              hipStream_t stream) {
    const float* x  = (const float*)d_in[0];
    const int*   ei = (const int*)d_in[1];
    const float* W1 = (const float*)d_in[2];
    const float* b1 = (const float*)d_in[3];
    const float* W2 = (const float*)d_in[4];
    const float* b2 = (const float*)d_in[5];
    float* out = (float*)d_out;

    const int n = NNODES;
    const int E = in_sizes[1] / 2;
    const int nb = (n + 255) / 256;

    char* ws = (char*)d_ws;
    size_t off = 0;
    auto alloc = [&](size_t bytes) -> char* {
        char* p = ws + off;
        off += (bytes + 255) & ~(size_t)255;
        return p;
    };
    float*  dinv     = (float*)alloc((size_t)n * 4);
    int*    counts   = (int*)alloc((size_t)n * 4);
    int*    offsets  = (int*)alloc((size_t)(n + 1) * 4);
    int*    cursor   = (int*)alloc((size_t)n * 4);
    int*    bsums    = (int*)alloc((size_t)nb * 4);
    int2*   csr_e    = (int2*)alloc((size_t)E * 8);
    bf16_t* Wf1      = (bf16_t*)alloc((size_t)DIM * DIM * 2);
    bf16_t* Wf2      = (bf16_t*)alloc((size_t)DIM * DIM * 2);
    bf16_t* P        = (bf16_t*)alloc((size_t)n * DIM * 2);   // GEMM output (bf16, row-major)
    bf16_t* X2       = (bf16_t*)alloc((size_t)n * DIM * 2);   // inter-layer activation (bf16)

    hipMemsetAsync(counts, 0, (size_t)n * 4, stream);
    hist_kernel<<<(E + 255) / 256, 256, 0, stream>>>(ei, E, counts);
    scanA_kernel<<<nb, 256, 0, stream>>>(counts, offsets, bsums, n);
    scanB_kernel<<<1, 256, 0, stream>>>(bsums, nb);
    scanC_kernel<<<nb, 256, 0, stream>>>(counts, bsums, offsets, dinv, cursor, n);
    scatter_kernel<<<(E + 255) / 256, 256, 0, stream>>>(ei, E, dinv, cursor, csr_e);

    convert_w_kernel<<<dim3(DIM, 2), DIM, 0, stream>>>(W1, W2, Wf1, Wf2);

    int tiles = (n + 15) / 16;                 // 3125 (exact: 50000 = 16*3125)
    int gemm_blocks = (tiles + 3) / 4;         // 782
    int agg_blocks = (n + 7) / 8;              // 6250

    gemm_kernel<true><<<gemm_blocks, 256, 0, stream>>>(x, Wf1, P, tiles);
    aggregate_kernel<1><<<agg_blocks, 256, 0, stream>>>(P, offsets, csr_e, dinv, b1, X2, n);
    gemm_kernel<false><<<gemm_blocks, 256, 0, stream>>>(X2, Wf2, P, tiles);
    aggregate_kernel<0><<<agg_blocks, 256, 0, stream>>>(P, offsets, csr_e, dinv, b2, out, n);
}

// Round 9
// 251.952 us; speedup vs baseline: 3.3775x; 1.0249x over previous
//
#include <hip/hip_runtime.h>
#include <stdint.h>

typedef __bf16 bf16_t;
typedef bf16_t bf16x4 __attribute__((ext_vector_type(4)));
typedef bf16_t bf16x8 __attribute__((ext_vector_type(8)));
typedef float f32x4 __attribute__((ext_vector_type(4)));

#define DIM 256
#define NNODES 50000

// ---------------- edge dtype detection (int64 vs int32), per-wave inline ----------------
// int64 edges: odd 4B words are high halves == 0 for values < 2^31.
__device__ __forceinline__ int detect_f64(const int* __restrict__ ei) {
    int v = ei[2 * (threadIdx.x & 63) + 1];
    unsigned long long m = __ballot(v == 0);
    return __popcll(m) > 32;
}

__device__ __forceinline__ int load_edge(const int* __restrict__ ei, int E, int f64,
                                         int which /*0=src,1=dst*/, int e) {
    int v = f64 ? ei[(size_t)which * 2 * E + 2 * (size_t)e]   // int64 low word (LE)
                : ei[(size_t)which * E + (size_t)e];
    return min(max(v, 0), NNODES - 1);
}

// ---------------- prep: zero counts + convert W (fp32 row-major -> fragment-order bf16) ----
// Blocks [0,196): zero counts. Blocks [196, 196+512): convert one W row each
// (cw&256 selects layer, k = cw&255). Wf layout: slice s=k>>5; frag f=nt*64+quad*16+m;
// flat short index s*8192 + f*8 + j (j=k&7) -- sequential LDS staging, conflict-free reads.

__global__ __launch_bounds__(256) void prep_kernel(int* __restrict__ counts,
                                                   const float* __restrict__ W1,
                                                   const float* __restrict__ W2,
                                                   bf16_t* __restrict__ Wf1,
                                                   bf16_t* __restrict__ Wf2, int n) {
    const int nb = (NNODES + 255) / 256;   // 196
    int b = blockIdx.x, t = threadIdx.x;
    if (b < nb) {
        int idx = b * 256 + t;
        if (idx < n) counts[idx] = 0;
    } else {
        int cw = b - nb;                   // 0..511
        const float* W = (cw & 256) ? W2 : W1;
        bf16_t* Wf = (cw & 256) ? Wf2 : Wf1;
        int k = cw & 255;
        int s = k >> 5, quad = (k >> 3) & 3, j = k & 7;
        int nt = t >> 4, m = t & 15;
        Wf[s * 8192 + (nt * 64 + quad * 16 + m) * 8 + j] = (bf16_t)W[k * DIM + t];
    }
}

// ---------------- GEMM1 + hist fused (independent work, one dispatch) ----------------
// Blocks [0, gemm_blocks): GEMM layer 1 (fp32 A). Blocks beyond: edge histogram.
// hist rides in GEMM1's occupancy shadow (atomic/VMEM pipe vs MFMA pipe co-schedule).

__global__ __launch_bounds__(256, 4) void gemm1_hist_kernel(const float* __restrict__ X,
                                                            const bf16_t* __restrict__ Wf,
                                                            bf16_t* __restrict__ H, int tiles,
                                                            int gemm_blocks,
                                                            const int* __restrict__ ei, int E,
                                                            int* __restrict__ counts) {
    __shared__ bf16_t sB[8192];               // 256n x 32k slice, fragment order
    if ((int)blockIdx.x >= gemm_blocks) {
        int f64 = detect_f64(ei);
        int e = (blockIdx.x - gemm_blocks) * 256 + threadIdx.x;
        if (e < E) atomicAdd(&counts[load_edge(ei, E, f64, 1, e)], 1);
        return;
    }

    int tid = threadIdx.x;
    int wave = tid >> 6, lane = tid & 63;
    int m = lane & 15, quad = lane >> 4;
    int tile = blockIdx.x * 4 + wave;
    bool active = tile < tiles;
    int arow = (min(tile, tiles - 1)) * 16 + m;   // clamped; store predicated below

    f32x4 acc[16] = {};

    for (int s = 0; s < 8; s++) {
        __syncthreads();                      // protect previous slice's reads
        {
            const bf16x8* g = (const bf16x8*)Wf + s * 1024;
            bf16x8* d = (bf16x8*)sB;
            #pragma unroll
            for (int it = 0; it < 4; it++) d[tid + it * 256] = g[tid + it * 256];
        }
        __syncthreads();

        // A fragment: A[m=lane&15][k = s*32 + quad*8 + j], fp32 -> bf16
        bf16x8 a;
        const f32x4* xp = (const f32x4*)(X + (size_t)arow * DIM + s * 32 + quad * 8);
        f32x4 x0 = xp[0], x1 = xp[1];
        #pragma unroll
        for (int j = 0; j < 4; j++) { a[j] = (bf16_t)x0[j]; a[j + 4] = (bf16_t)x1[j]; }

        #pragma unroll
        for (int nt = 0; nt < 16; nt++) {
            bf16x8 b = *(const bf16x8*)(sB + nt * 512 + lane * 8);  // sequential: no conflicts
            acc[nt] = __builtin_amdgcn_mfma_f32_16x16x32_bf16(a, b, acc[nt], 0, 0, 0);
        }
    }

    if (active) {
        int rowb = tile * 16 + quad * 4;
        #pragma unroll
        for (int nt = 0; nt < 16; nt++) {
            #pragma unroll
            for (int r = 0; r < 4; r++) {
                H[(size_t)(rowb + r) * DIM + nt * 16 + m] = (bf16_t)acc[nt][r];
            }
        }
    }
}

// ---------------- one-dispatch scan, zero synchronization ----------------
// Replaces scanA/B/C. Each block redundantly sums ALL preceding counts (<=195KB,
// L2-resident; ~19MB total across blocks ~= 2us) -- no cross-block handshake (r7 lesson:
// coordination serializes). Then local inclusive scan; emits offsets, cursor, dinv.

__global__ __launch_bounds__(256) void scan_kernel(const int* __restrict__ counts,
                                                   int* __restrict__ offsets,
                                                   int* __restrict__ cursor,
                                                   float* __restrict__ dinv, int n) {
    __shared__ int red[256];
    __shared__ int sm[256];
    int b = blockIdx.x, t = threadIdx.x;

    // base = sum counts[0 .. b*256)
    int part = 0;
    const int4* c4 = (const int4*)counts;
    int lim = b * 64;
    for (int j = t; j < lim; j += 256) {
        int4 v = c4[j];
        part += v.x + v.y + v.z + v.w;
    }
    red[t] = part;
    __syncthreads();
    #pragma unroll
    for (int off = 128; off > 0; off >>= 1) {
        if (t < off) red[t] += red[t + off];
        __syncthreads();
    }
    int base = red[0];

    // local inclusive scan of this block's 256 counts
    int idx = b * 256 + t;
    int v = (idx < n) ? counts[idx] : 0;
    sm[t] = v;
    __syncthreads();
    #pragma unroll
    for (int off = 1; off < 256; off <<= 1) {
        int u = (t >= off) ? sm[t - off] : 0;
        __syncthreads();
        sm[t] += u;
        __syncthreads();
    }
    if (idx < n) {
        int incl = base + sm[t];
        offsets[idx + 1] = incl;
        cursor[idx] = incl - v;
        dinv[idx] = rsqrtf((float)(v + 1));  // +1 self-loop
    }
    if (idx == 0) offsets[0] = 0;
}

// csr_e[pos] = {src, norm_bits} packed 8B.
__global__ void scatter_kernel(const int* __restrict__ ei, int E,
                               const float* __restrict__ dinv, int* __restrict__ cursor,
                               int2* __restrict__ csr_e) {
    int f64 = detect_f64(ei);
    int e = blockIdx.x * blockDim.x + threadIdx.x;
    if (e < E) {
        int s = load_edge(ei, E, f64, 0, e);
        int d = load_edge(ei, E, f64, 1, e);
        int pos = atomicAdd(&cursor[d], 1);
        if (pos >= 0 && pos < E) {
            int2 v;
            v.x = s;
            v.y = __float_as_int(dinv[s] * dinv[d]);
            csr_e[pos] = v;
        }
    }
}

// ---------------- GEMM layer 2: H = X2(bf16) @ W2 ----------------

__global__ __launch_bounds__(256, 4) void gemm_kernel(const bf16_t* __restrict__ Xv,
                                                      const bf16_t* __restrict__ Wf,
                                                      bf16_t* __restrict__ H, int tiles) {
    __shared__ bf16_t sB[8192];               // 256n x 32k slice, fragment order
    int tid = threadIdx.x;
    int wave = tid >> 6, lane = tid & 63;
    int m = lane & 15, quad = lane >> 4;
    int tile = blockIdx.x * 4 + wave;
    bool active = tile < tiles;
    int arow = (min(tile, tiles - 1)) * 16 + m;   // clamped; store predicated below

    f32x4 acc[16] = {};

    for (int s = 0; s < 8; s++) {
        __syncthreads();                      // protect previous slice's reads
        {
            const bf16x8* g = (const bf16x8*)Wf + s * 1024;
            bf16x8* d = (bf16x8*)sB;
            #pragma unroll
            for (int it = 0; it < 4; it++) d[tid + it * 256] = g[tid + it * 256];
        }
        __syncthreads();

        bf16x8 a = *(const bf16x8*)(Xv + (size_t)arow * DIM + s * 32 + quad * 8);

        #pragma unroll
        for (int nt = 0; nt < 16; nt++) {
            bf16x8 b = *(const bf16x8*)(sB + nt * 512 + lane * 8);  // sequential: no conflicts
            acc[nt] = __builtin_amdgcn_mfma_f32_16x16x32_bf16(a, b, acc[nt], 0, 0, 0);
        }
    }

    if (active) {
        int rowb = tile * 16 + quad * 4;
        #pragma unroll
        for (int nt = 0; nt < 16; nt++) {
            #pragma unroll
            for (int r = 0; r < 4; r++) {
                H[(size_t)(rowb + r) * DIM + nt * 16 + m] = (bf16_t)acc[nt][r];
            }
        }
    }
}

// ---------------- Aggregation (round-8 version, at its service ceiling) ----------------
// 32-lane group per node; lane owns 8 dims (bf16x8 = 16B); same-address edge-meta loads
// HW-broadcast; 8 gathers issued per batch with a sched_barrier fence before consume.

template <int OUT_BF16>
__global__ __launch_bounds__(256) void aggregate_kernel(const bf16_t* __restrict__ H,
                                                        const int* __restrict__ offsets,
                                                        const int2* __restrict__ csr_e,
                                                        const float* __restrict__ dinv,
                                                        const float* __restrict__ bias,
                                                        void* __restrict__ outv, int n) {
    int wg = threadIdx.x >> 5;     // 8 node-groups per block
    int l = threadIdx.x & 31;      // lane in group: dims l*8 .. l*8+7
    int i = blockIdx.x * 8 + wg;
    if (i >= n) return;

    const char* Hb = (const char*)H;
    int doff = l * 16;

    auto cvt = [](bf16x4 v) -> f32x4 {
        f32x4 r;
        #pragma unroll
        for (int j = 0; j < 4; j++) r[j] = (float)v[j];
        return r;
    };
    auto lo4 = [](bf16x8 v) -> bf16x4 { return __builtin_shufflevector(v, v, 0, 1, 2, 3); };
    auto hi4 = [](bf16x8 v) -> bf16x4 { return __builtin_shufflevector(v, v, 4, 5, 6, 7); };

    float dii = dinv[i];
    bf16x8 selfv = *(const bf16x8*)(Hb + ((size_t)i << 9) + doff);
    f32x4 acc0 = cvt(lo4(selfv)) * (dii * dii);
    f32x4 acc1 = cvt(hi4(selfv)) * (dii * dii);

    int e0 = offsets[i], e1 = offsets[i + 1];
    int e = e0;
    for (; e + 8 <= e1; e += 8) {
        unsigned s[8]; float w[8];
        #pragma unroll
        for (int j = 0; j < 8; j++) {
            int2 t = csr_e[e + j];
            s[j] = min((unsigned)t.x, (unsigned)(NNODES - 1));
            w[j] = __int_as_float(t.y);
        }
        bf16x8 h[8];
        #pragma unroll
        for (int j = 0; j < 8; j++) {
            h[j] = *(const bf16x8*)(Hb + ((size_t)s[j] << 9) + doff);
        }
        __builtin_amdgcn_sched_barrier(0);   // all 8 gathers issued before any consume
        #pragma unroll
        for (int j = 0; j < 8; j++) {
            acc0 += cvt(lo4(h[j])) * w[j];
            acc1 += cvt(hi4(h[j])) * w[j];
        }
    }
    if (e < e1) {
        unsigned s[8]; float w[8];
        #pragma unroll
        for (int j = 0; j < 8; j++) {
            bool valid = (e + j) < e1;
            int2 t = csr_e[valid ? e + j : e];   // e < e1 so csr_e[e] is safe
            if (!valid) { t.x = i; t.y = 0; }    // pad: self row (L1-hot), zero weight
            s[j] = min((unsigned)t.x, (unsigned)(NNODES - 1));
            w[j] = __int_as_float(t.y);
        }
        bf16x8 h[8];
        #pragma unroll
        for (int j = 0; j < 8; j++) {
            h[j] = *(const bf16x8*)(Hb + ((size_t)s[j] << 9) + doff);
        }
        __builtin_amdgcn_sched_barrier(0);   // all 8 gathers issued before any consume
        #pragma unroll
        for (int j = 0; j < 8; j++) {
            acc0 += cvt(lo4(h[j])) * w[j];
            acc1 += cvt(hi4(h[j])) * w[j];
        }
    }

    const f32x4* bp = (const f32x4*)(bias + l * 8);
    acc0 += bp[0];
    acc1 += bp[1];
    #pragma unroll
    for (int j = 0; j < 4; j++) {
        acc0[j] = fmaxf(acc0[j], 0.0f);
        acc1[j] = fmaxf(acc1[j], 0.0f);
    }

    if (OUT_BF16) {
        bf16x8 o;
        #pragma unroll
        for (int j = 0; j < 4; j++) { o[j] = (bf16_t)acc0[j]; o[j + 4] = (bf16_t)acc1[j]; }
        *(bf16x8*)((bf16_t*)outv + (size_t)i * DIM + l * 8) = o;
    } else {
        float* op = (float*)outv + (size_t)i * DIM + l * 8;
        *(f32x4*)op = acc0;
        *(f32x4*)(op + 4) = acc1;
    }
}

// ---------------- launch ----------------

extern "C" void kernel_launch(void* const* d_in, const int* in_sizes, int n_in,
                              void* d_out, int out_size, void* d_ws, size_t ws_size,
                              hipStream_t stream) {
    const float* x  = (const float*)d_in[0];
    const int*   ei = (const int*)d_in[1];
    const float* W1 = (const float*)d_in[2];
    const float* b1 = (const float*)d_in[3];
    const float* W2 = (const float*)d_in[4];
    const float* b2 = (const float*)d_in[5];
    float* out = (float*)d_out;

    const int n = NNODES;
    const int E = in_sizes[1] / 2;
    const int nb = (n + 255) / 256;            // 196

    char* ws = (char*)d_ws;
    size_t off = 0;
    auto alloc = [&](size_t bytes) -> char* {
        char* p = ws + off;
        off += (bytes + 255) & ~(size_t)255;
        return p;
    };
    float*  dinv     = (float*)alloc((size_t)n * 4);
    int*    counts   = (int*)alloc((size_t)n * 4);
    int*    offsets  = (int*)alloc((size_t)(n + 1) * 4);
    int*    cursor   = (int*)alloc((size_t)n * 4);
    int2*   csr_e    = (int2*)alloc((size_t)E * 8);
    bf16_t* Wf1      = (bf16_t*)alloc((size_t)DIM * DIM * 2);
    bf16_t* Wf2      = (bf16_t*)alloc((size_t)DIM * DIM * 2);
    bf16_t* P        = (bf16_t*)alloc((size_t)n * DIM * 2);   // GEMM output (bf16, row-major)
    bf16_t* X2       = (bf16_t*)alloc((size_t)n * DIM * 2);   // inter-layer activation (bf16)

    int tiles = (n + 15) / 16;                 // 3125 (exact: 50000 = 16*3125)
    int gemm_blocks = (tiles + 3) / 4;         // 782
    int hist_blocks = (E + 255) / 256;         // 1563
    int agg_blocks = (n + 7) / 8;              // 6250

    // 1: zero counts + convert both W (independent, one dispatch)
    prep_kernel<<<nb + 512, 256, 0, stream>>>(counts, W1, W2, Wf1, Wf2, n);
    // 2: GEMM layer 1 with edge histogram fused in its occupancy shadow
    gemm1_hist_kernel<<<gemm_blocks + hist_blocks, 256, 0, stream>>>(x, Wf1, P, tiles,
                                                                     gemm_blocks, ei, E, counts);
    // 3: one-dispatch scan (offsets, cursor, dinv)
    scan_kernel<<<nb, 256, 0, stream>>>(counts, offsets, cursor, dinv, n);
    // 4: CSR scatter
    scatter_kernel<<<hist_blocks, 256, 0, stream>>>(ei, E, dinv, cursor, csr_e);
    // 5-7: agg1, gemm2, agg2
    aggregate_kernel<1><<<agg_blocks, 256, 0, stream>>>(P, offsets, csr_e, dinv, b1, X2, n);
    gemm_kernel<<<gemm_blocks, 256, 0, stream>>>(X2, Wf2, P, tiles);
    aggregate_kernel<0><<<agg_blocks, 256, 0, stream>>>(P, offsets, csr_e, dinv, b2, out, n);
}